// Round 16
// baseline (689.822 us; speedup 1.0000x reference)
//
#include <hip/hip_runtime.h>
#include <hip/hip_cooperative_groups.h>
#include <stdint.h>

namespace cg = cooperative_groups;

#define SGRID 128
#define CAP 4096
#define NBLK 1024   // cooperative grid: 4 blocks/CU x 256 CUs

typedef _Float16 f16;
typedef f16 f16x8 __attribute__((ext_vector_type(8)));
typedef float f32x4 __attribute__((ext_vector_type(4)));
typedef unsigned long long u64;

static __device__ __forceinline__ f32x4 mfma16(uint4 a, uint4 b, f32x4 c) {
    union { uint4 u; f16x8 v; } ua, ub;
    ua.u = a; ub.u = b;
    return __builtin_amdgcn_mfma_f32_16x16x32_f16(ua.v, ub.v, c, 0, 0, 0);
}

static __device__ __forceinline__ void split8(const float* v, uint4& hu, uint4& lu) {
    union { f16 h[8]; uint4 u; } hv, lv;
    #pragma unroll
    for (int j = 0; j < 8; ++j) {
        f16 h = (f16)v[j];
        hv.h[j] = h;
        lv.h[j] = (f16)(v[j] - (float)h);
    }
    hu = hv.u; lu = lv.u;
}

// ---- center tap tail: B-frags loaded; one wave = 32 points x 64 cout ----
static __device__ __forceinline__ void center_tail(
    const float* __restrict__ A, const uint4 b[2][4],
    float* __restrict__ O, int N, int gw, int lane)
{
    const int r = lane & 15, lq = lane >> 4;
    const int p0 = gw * 32;

    uint4 ah[2][2], al[2][2];
    #pragma unroll
    for (int rt = 0; rt < 2; ++rt) {
        int row = p0 + rt * 16 + r;
        #pragma unroll
        for (int ks = 0; ks < 2; ++ks) {
            float v[8];
            if (row < N) {
                float4 v0 = *(const float4*)(A + (size_t)row * 64 + ks * 32 + lq * 8);
                float4 v1 = *(const float4*)(A + (size_t)row * 64 + ks * 32 + lq * 8 + 4);
                v[0]=v0.x; v[1]=v0.y; v[2]=v0.z; v[3]=v0.w;
                v[4]=v1.x; v[5]=v1.y; v[6]=v1.z; v[7]=v1.w;
            } else {
                #pragma unroll
                for (int j = 0; j < 8; ++j) v[j] = 0.f;
            }
            split8(v, ah[rt][ks], al[rt][ks]);
        }
    }

    f32x4 acc[2][4];
    #pragma unroll
    for (int i = 0; i < 2; ++i)
        #pragma unroll
        for (int j = 0; j < 4; ++j) acc[i][j] = (f32x4){0.f, 0.f, 0.f, 0.f};

    #pragma unroll
    for (int ks = 0; ks < 2; ++ks)
        #pragma unroll
        for (int rt = 0; rt < 2; ++rt)
            #pragma unroll
            for (int ct = 0; ct < 4; ++ct) {
                acc[rt][ct] = mfma16(ah[rt][ks], b[ks][ct], acc[rt][ct]);
                acc[rt][ct] = mfma16(al[rt][ks], b[ks][ct], acc[rt][ct]);
            }

    #pragma unroll
    for (int rt = 0; rt < 2; ++rt)
        #pragma unroll
        for (int j = 0; j < 4; ++j) {
            int row = p0 + rt * 16 + lq * 4 + j;
            if (row < N) {
                #pragma unroll
                for (int ct = 0; ct < 4; ++ct)
                    O[(size_t)row * 64 + ct * 16 + r] = acc[rt][ct][j];
            }
        }
}

// ---- sparse pair task: one wave = 16 pairs x 32 couts (ch half) ----
static __device__ __forceinline__ void sparse_task(
    const float* __restrict__ A, const f16* __restrict__ Wp,
    const int* __restrict__ pin, const int* __restrict__ pout,
    const int* __restrict__ cnt, float* __restrict__ O, int w, int lane)
{
    int slot  = w >> 9;
    int rem   = w & 511;
    int chunk = rem >> 1;
    int ch    = rem & 1;
    int cn = cnt[slot * 16]; if (cn > CAP) cn = CAP;
    int i0 = chunk * 16;
    if (i0 >= cn) return;
    int o = slot < 13 ? slot : slot + 1;
    const int r = lane & 15, lq = lane >> 4;

    const uint4* wb = (const uint4*)Wp + (size_t)o * 512 + lane;
    uint4 b[2][2];
    #pragma unroll
    for (int ct = 0; ct < 2; ++ct)
        #pragma unroll
        for (int ks = 0; ks < 2; ++ks)
            b[ct][ks] = wb[((ch * 2 + ct) * 2 + ks) * 64];

    int p = i0 + r;
    int in = (p < cn) ? pin[slot * CAP + p] : -1;
    uint4 ah[2], al[2];
    #pragma unroll
    for (int ks = 0; ks < 2; ++ks) {
        float v[8];
        if (in >= 0) {
            float4 v0 = *(const float4*)(A + (size_t)in * 64 + ks * 32 + lq * 8);
            float4 v1 = *(const float4*)(A + (size_t)in * 64 + ks * 32 + lq * 8 + 4);
            v[0]=v0.x; v[1]=v0.y; v[2]=v0.z; v[3]=v0.w;
            v[4]=v1.x; v[5]=v1.y; v[6]=v1.z; v[7]=v1.w;
        } else {
            #pragma unroll
            for (int j = 0; j < 8; ++j) v[j] = 0.f;
        }
        split8(v, ah[ks], al[ks]);
    }

    f32x4 acc[2];
    acc[0] = (f32x4){0.f, 0.f, 0.f, 0.f};
    acc[1] = (f32x4){0.f, 0.f, 0.f, 0.f};
    #pragma unroll
    for (int ks = 0; ks < 2; ++ks)
        #pragma unroll
        for (int ct = 0; ct < 2; ++ct) {
            acc[ct] = mfma16(ah[ks], b[ct][ks], acc[ct]);
            acc[ct] = mfma16(al[ks], b[ct][ks], acc[ct]);
        }

    #pragma unroll
    for (int j = 0; j < 4; ++j) {
        int pr = i0 + lq * 4 + j;
        if (pr < cn) {
            int oidx = pout[slot * CAP + pr];
            #pragma unroll
            for (int ct = 0; ct < 2; ++ct)
                atomicAdd(&O[(size_t)oidx * 64 + (ch * 2 + ct) * 16 + r], acc[ct][j]);
        }
    }
}

// ---- build body: window probe + parallel 26-load emit for point chunk ck ----
static __device__ __forceinline__ void build_body(
    const int* __restrict__ coords, const int* __restrict__ table,
    const unsigned* __restrict__ bitmap,
    int* __restrict__ pin, int* __restrict__ pout, int* __restrict__ cnt,
    int N, int ck, int tid, u64 (*sbal)[4], int (*sbase4)[4])
{
    const int lane = tid & 63, wave = tid >> 6;
    const int n = ck * 256 + tid;
    const bool valid = n < N;

    int4 c = {0, 0, 0, 0};
    if (valid) c = ((const int4*)coords)[n];
    const int z  = c.w;
    const int zb = (z == 0) ? 0 : z - 1;
    const int wofs = zb >> 5, sh = zb & 31;

    unsigned omask = 0;
    #pragma unroll
    for (int cidx = 0; cidx < 9; ++cidx) {
        int dx = cidx / 3 - 1, dy = cidx % 3 - 1;
        int qx = c.y + dx, qy = c.z + dy;
        bool colok = valid && ((unsigned)qx < SGRID) && ((unsigned)qy < SGRID);
        int wi = colok ? ((((c.x * SGRID + qx) * SGRID + qy) << 2) + wofs) : 0;
        unsigned w0 = bitmap[wi];
        unsigned w1 = bitmap[wi + 1];
        u64 w = (u64)w0 | ((u64)w1 << 32);
        unsigned t = (unsigned)(w >> sh) & 7u;
        if (z == 0)         t = (t << 1) & 6u;
        if (z == SGRID - 1) t &= 3u;
        t = colok ? t : 0u;
        omask |= t << (cidx * 3);
    }
    omask &= ~(1u << 13);

    const int key = ((c.x * SGRID + c.y) * SGRID + c.z) * SGRID + z;
    int nb[26];
    #pragma unroll
    for (int s = 0; s < 26; ++s) {
        int o = s < 13 ? s : s + 1;
        bool occ = (omask >> o) & 1u;
        int qkey = key + (o / 9 - 1) * SGRID * SGRID + ((o / 3) % 3 - 1) * SGRID + (o % 3 - 1);
        int v = table[occ ? qkey : 0];
        nb[s] = occ ? v : -1;
    }

    #pragma unroll
    for (int s = 0; s < 26; ++s) {
        u64 bal = __ballot(nb[s] >= 0);
        if (lane == 0) sbal[s][wave] = bal;
    }
    __syncthreads();

    if (tid < 26) {
        int c0 = (int)__popcll(sbal[tid][0]);
        int c1 = (int)__popcll(sbal[tid][1]);
        int c2 = (int)__popcll(sbal[tid][2]);
        int c3 = (int)__popcll(sbal[tid][3]);
        int tot = c0 + c1 + c2 + c3;
        int base = tot ? atomicAdd(&cnt[tid * 16], tot) : 0;
        sbase4[tid][0] = base;
        sbase4[tid][1] = base + c0;
        sbase4[tid][2] = base + c0 + c1;
        sbase4[tid][3] = base + c0 + c1 + c2;
    }
    __syncthreads();

    const u64 ltmask = (1ull << lane) - 1ull;
    #pragma unroll
    for (int s = 0; s < 26; ++s) {
        if (nb[s] >= 0) {
            int pos = sbase4[s][wave] + (int)__popcll(sbal[s][wave] & ltmask);
            if (pos < CAP) {
                pin[s * CAP + pos]  = nb[s];
                pout[s * CAP + pos] = n;
            }
        }
    }
    __syncthreads();
}

// ---- W-prep item: one uint4 fragment ----
static __device__ __forceinline__ void wprep_item(
    const float* __restrict__ W1, const float* __restrict__ W2,
    f16* __restrict__ Wp1, f16* __restrict__ Wp2, int idx)
{
    const int half = 27 * 512;
    const float* W = (idx < half) ? W1 : W2;
    f16* Wp = (idx < half) ? Wp1 : Wp2;
    int id = (idx < half) ? idx : idx - half;
    int lane = id & 63;
    int ks = (id >> 6) & 1;
    int ct = (id >> 7) & 3;
    int o  = id >> 9;
    int co  = ct * 16 + (lane & 15);
    int ci0 = ks * 32 + (lane >> 4) * 8;
    union { f16 h[8]; uint4 u; } hv;
    #pragma unroll
    for (int j = 0; j < 8; ++j)
        hv.h[j] = (f16)W[((size_t)o * 64 + ci0 + j) * 64 + co];
    ((uint4*)Wp)[id] = hv.u;
}

// ---- center1 B-frags from raw W1[13] ----
static __device__ __forceinline__ void w1_center_frags(
    const float* __restrict__ W1, uint4 b[2][4], int lane)
{
    const float* Wc = W1 + 13 * 4096;
    #pragma unroll
    for (int ct = 0; ct < 4; ++ct) {
        int co = ct * 16 + (lane & 15);
        #pragma unroll
        for (int ks = 0; ks < 2; ++ks) {
            int ci0 = ks * 32 + (lane >> 4) * 8;
            union { f16 h[8]; uint4 u; } hv;
            #pragma unroll
            for (int j = 0; j < 8; ++j)
                hv.h[j] = (f16)Wc[(ci0 + j) * 64 + co];
            b[ks][ct] = hv.u;
        }
    }
}

// ================== THE FUSED COOPERATIVE KERNEL ==================
__global__ void __launch_bounds__(256, 4) fused(
    const float* __restrict__ F, const int* __restrict__ coords,
    const float* __restrict__ W1, const float* __restrict__ W2,
    int* __restrict__ table, unsigned* __restrict__ bitmap,
    int* __restrict__ cnt, int* __restrict__ pin, int* __restrict__ pout,
    float* __restrict__ H, f16* __restrict__ Wp1, f16* __restrict__ Wp2,
    float* __restrict__ out, int N, int bm4)
{
    cg::grid_group grid = cg::this_grid();
    __shared__ u64 sbal[26][4];
    __shared__ int sbase4[26][4];

    const int tid  = threadIdx.x;
    const int bid  = blockIdx.x;
    const int lane = tid & 63;
    const int wv   = tid >> 6;
    const int gwave = bid * 4 + wv;
    const int ngroups = (N + 31) >> 5;

    // ---- P0: center1 (blocks 0..781) | Wprep (782..889) | clear (890..1023) ----
    if (bid < 782) {
        uint4 b[2][4];
        w1_center_frags(W1, b, lane);
        for (int gw = gwave; gw < ngroups; gw += 782 * 4)
            center_tail(F, b, H, N, gw, lane);
    } else if (bid < 890) {
        int idx = (bid - 782) * 256 + tid;     // 0..27647
        wprep_item(W1, W2, Wp1, Wp2, idx);
    } else {
        uint4* b4 = (uint4*)bitmap;
        for (int i = (bid - 890) * 256 + tid; i < bm4; i += 134 * 256)
            b4[i] = (uint4){0, 0, 0, 0};
        if (bid == 890 && tid < 26) cnt[tid * 16] = 0;
    }
    grid.sync();

    // ---- P1: scatter table + bitmap ----
    for (int i = bid * 256 + tid; i < N; i += NBLK * 256) {
        int4 c = ((const int4*)coords)[i];
        int key = ((c.x * SGRID + c.y) * SGRID + c.z) * SGRID + c.w;
        table[key] = i;
        atomicOr(&bitmap[key >> 5], 1u << (key & 31));
    }
    grid.sync();

    // ---- P2: build pair lists ----
    {
        const int chunks = (N + 255) >> 8;
        for (int ck = bid; ck < chunks; ck += NBLK)
            build_body(coords, table, bitmap, pin, pout, cnt, N, ck, tid, sbal, sbase4);
    }
    grid.sync();

    // ---- P3: sparse layer 1 (F -> H atomic) ----
    for (int w = gwave; w < 26 * 512; w += NBLK * 4)
        sparse_task(F, Wp1, pin, pout, cnt, H, w, lane);
    grid.sync();

    // ---- P4: center layer 2 (H -> out plain) ----
    {
        const uint4* wb = (const uint4*)Wp2 + 13 * 512 + lane;
        uint4 b[2][4];
        #pragma unroll
        for (int ct = 0; ct < 4; ++ct)
            #pragma unroll
            for (int ks = 0; ks < 2; ++ks)
                b[ks][ct] = wb[(ct * 2 + ks) * 64];
        for (int gw = gwave; gw < ngroups; gw += NBLK * 4)
            center_tail(H, b, out, N, gw, lane);
    }
    grid.sync();

    // ---- P5: sparse layer 2 (H -> out atomic) ----
    for (int w = gwave; w < 26 * 512; w += NBLK * 4)
        sparse_task(H, Wp2, pin, pout, cnt, out, w, lane);
}

// ================== FALLBACK PATH (R15's proven 6-kernel chain) ==================
__global__ void clear_meta(uint4* __restrict__ bitmap4, int nwords4, int* __restrict__ cnt) {
    const int stride = gridDim.x * 256;
    for (int i = blockIdx.x * 256 + threadIdx.x; i < nwords4; i += stride)
        bitmap4[i] = (uint4){0, 0, 0, 0};
    if (blockIdx.x == 0 && threadIdx.x < 26) cnt[threadIdx.x * 16] = 0;
}

__global__ void __launch_bounds__(256) prep_center(
    const float* __restrict__ F, const float* __restrict__ W1, float* __restrict__ H,
    const int* __restrict__ coords, int* __restrict__ table, unsigned* __restrict__ bitmap,
    const float* __restrict__ W2, f16* __restrict__ Wp1, f16* __restrict__ Wp2,
    int N, int centerB, int scatB)
{
    const int tid = threadIdx.x;
    int bid = blockIdx.x;
    if (bid < centerB) {
        int gw = (bid * 256 + tid) >> 6;
        if (gw >= (N + 31) >> 5) return;
        uint4 b[2][4];
        w1_center_frags(W1, b, tid & 63);
        center_tail(F, b, H, N, gw, tid & 63);
        return;
    }
    bid -= centerB;
    if (bid < scatB) {
        int i = bid * 256 + tid;
        if (i < N) {
            int4 c = ((const int4*)coords)[i];
            int key = ((c.x * SGRID + c.y) * SGRID + c.z) * SGRID + c.w;
            table[key] = i;
            atomicOr(&bitmap[key >> 5], 1u << (key & 31));
        }
        return;
    }
    bid -= scatB;
    wprep_item(W1, W2, Wp1, Wp2, bid * 256 + tid);
}

__global__ void __launch_bounds__(256) build(
    const int* __restrict__ coords, const int* __restrict__ table,
    const unsigned* __restrict__ bitmap,
    int* __restrict__ pin, int* __restrict__ pout, int* __restrict__ cnt, int N)
{
    __shared__ u64 sbal[26][4];
    __shared__ int sbase4[26][4];
    build_body(coords, table, bitmap, pin, pout, cnt, N, blockIdx.x, threadIdx.x, sbal, sbase4);
}

__global__ void __launch_bounds__(256) conv_center(
    const float* __restrict__ A, const f16* __restrict__ Wp,
    float* __restrict__ O, int N)
{
    int gw = (blockIdx.x * 256 + threadIdx.x) >> 6;
    if (gw >= (N + 31) >> 5) return;
    const int lane = threadIdx.x & 63;
    const uint4* wb = (const uint4*)Wp + 13 * 512 + lane;
    uint4 b[2][4];
    #pragma unroll
    for (int ct = 0; ct < 4; ++ct)
        #pragma unroll
        for (int ks = 0; ks < 2; ++ks)
            b[ks][ct] = wb[(ct * 2 + ks) * 64];
    center_tail(A, b, O, N, gw, lane);
}

__global__ void __launch_bounds__(256) conv_sparse(
    const float* __restrict__ A, const f16* __restrict__ Wp,
    const int* __restrict__ pin, const int* __restrict__ pout,
    const int* __restrict__ cnt, float* __restrict__ O)
{
    int w = (blockIdx.x * 256 + threadIdx.x) >> 6;
    if (w >= 26 * 512) return;
    sparse_task(A, Wp, pin, pout, cnt, O, w, threadIdx.x & 63);
}

extern "C" void kernel_launch(void* const* d_in, const int* in_sizes, int n_in,
                              void* d_out, int out_size, void* d_ws, size_t ws_size,
                              hipStream_t stream) {
    const float* feats  = (const float*)d_in[0];
    const int*   coords = (const int*)d_in[1];
    const float* W1     = (const float*)d_in[2];
    const float* W2     = (const float*)d_in[3];
    float* out = (float*)d_out;

    const int N = in_sizes[0] / 64;
    const size_t nvox = 2ull * SGRID * SGRID * SGRID;

    char* p = (char*)d_ws;
    int*      table  = (int*)p;      p += nvox * 4;          // no init (bitmap-guarded)
    unsigned* bitmap = (unsigned*)p; p += (nvox / 32) * 4;
    p += 16;                                                  // pad word (window overread)
    int*      cnt    = (int*)p;      p += 26 * 16 * 4;
    int*      pin    = (int*)p;      p += 26ull * CAP * 4;
    int*      pout   = (int*)p;      p += 26ull * CAP * 4;
    float*    H      = (float*)p;    p += (size_t)N * 64 * 4;
    f16*      Wp1    = (f16*)p;      p += 27ull * 4096 * 2;
    f16*      Wp2    = (f16*)p;      p += 27ull * 4096 * 2;

    int Nv   = N;
    int bm4v = (int)(nvox / 32 / 4) + 1;   // includes pad word

    void* kargs[] = {
        (void*)&feats, (void*)&coords, (void*)&W1, (void*)&W2,
        (void*)&table, (void*)&bitmap, (void*)&cnt, (void*)&pin, (void*)&pout,
        (void*)&H, (void*)&Wp1, (void*)&Wp2, (void*)&out, (void*)&Nv, (void*)&bm4v
    };
    hipError_t err = hipLaunchCooperativeKernel((void*)fused, dim3(NBLK), dim3(256),
                                                kargs, 0, stream);
    if (err != hipSuccess) {
        // fallback: R15's proven 6-dispatch chain
        const int scatB   = (N + 255) / 256;
        const int ngroups = (N + 31) / 32;
        const int centerB = (ngroups + 3) / 4;
        const int sparseB = 26 * 512 / 4;
        clear_meta<<<256, 256, 0, stream>>>((uint4*)bitmap, bm4v, cnt);
        prep_center<<<centerB + scatB + 108, 256, 0, stream>>>(
            feats, W1, H, coords, table, bitmap, W2, Wp1, Wp2, N, centerB, scatB);
        build<<<scatB, 256, 0, stream>>>(coords, table, bitmap, pin, pout, cnt, N);
        conv_sparse<<<sparseB, 256, 0, stream>>>(feats, Wp1, pin, pout, cnt, H);
        conv_center<<<centerB, 256, 0, stream>>>(H, Wp2, out, N);
        conv_sparse<<<sparseB, 256, 0, stream>>>(H, Wp2, pin, pout, cnt, out);
    }
}

// Round 17
// 95.050 us; speedup vs baseline: 7.2574x; 7.2574x over previous
//
#include <hip/hip_runtime.h>
#include <stdint.h>

#define SGRID 128
#define CAP 4096

typedef _Float16 f16;
typedef f16 f16x8 __attribute__((ext_vector_type(8)));
typedef float f32x4 __attribute__((ext_vector_type(4)));
typedef unsigned long long u64;

static __device__ __forceinline__ f32x4 mfma16(uint4 a, uint4 b, f32x4 c) {
    union { uint4 u; f16x8 v; } ua, ub;
    ua.u = a; ub.u = b;
    return __builtin_amdgcn_mfma_f32_16x16x32_f16(ua.v, ub.v, c, 0, 0, 0);
}

static __device__ __forceinline__ void split8(const float* v, uint4& hu, uint4& lu) {
    union { f16 h[8]; uint4 u; } hv, lv;
    #pragma unroll
    for (int j = 0; j < 8; ++j) {
        f16 h = (f16)v[j];
        hv.h[j] = h;
        lv.h[j] = (f16)(v[j] - (float)h);
    }
    hu = hv.u; lu = lv.u;
}

// async 16B global -> LDS (per-lane global src, wave-uniform LDS base + lane*16)
static __device__ __forceinline__ void gload16(const void* g, void* l) {
    __builtin_amdgcn_global_load_lds(
        (const __attribute__((address_space(1))) unsigned int*)g,
        (__attribute__((address_space(3))) unsigned int*)l, 16, 0, 0);
}

// read one A-row's hi/lo f16 fragments from rotated staged LDS.
// storage: slot s of local row rl holds 16B chunk (s+rl)&15 of the row.
static __device__ __forceinline__ void read_row_frags(
    const float* __restrict__ sW, int rl, int lq, uint4 ah[2], uint4 al[2])
{
    #pragma unroll
    for (int ks = 0; ks < 2; ++ks) {
        int c0 = ks * 8 + lq * 2;
        int s0 = (c0 - rl) & 15, s1 = (c0 + 1 - rl) & 15;
        float4 v0 = *(const float4*)&sW[(rl * 16 + s0) * 4];
        float4 v1 = *(const float4*)&sW[(rl * 16 + s1) * 4];
        float v[8] = {v0.x, v0.y, v0.z, v0.w, v1.x, v1.y, v1.z, v1.w};
        split8(v, ah[ks], al[ks]);
    }
}

// ---- staged center body: one wave = 32 rows x 64 cout; 8 async KB in flight ----
static __device__ __forceinline__ void center_staged(
    const float* __restrict__ A, const uint4 b[2][4], float* __restrict__ O,
    int N, int gw0, int tid, float* sF)
{
    const int w = tid >> 6, lane = tid & 63;
    const int r = lane & 15, lq = lane >> 4;
    const int gw = gw0 + w;
    const int p0 = gw * 32;
    float* sW = sF + w * 2048;     // 32 rows * 16 chunks * 4 floats

    #pragma unroll
    for (int j = 0; j < 8; ++j) {
        int ch = j * 64 + lane;
        int rl = ch >> 4, slot = ch & 15;
        int csrc = (slot + rl) & 15;
        int grow = p0 + rl;
        if (grow > N - 1) grow = N - 1;
        gload16(A + (size_t)grow * 64 + csrc * 4, sW + j * 256);
    }
    asm volatile("s_waitcnt vmcnt(0)" ::: "memory");
    __builtin_amdgcn_sched_barrier(0);
    if (p0 >= N) return;

    uint4 ah[2][2], al[2][2];
    #pragma unroll
    for (int rt = 0; rt < 2; ++rt)
        read_row_frags(sW, rt * 16 + r, lq, ah[rt], al[rt]);

    f32x4 acc[2][4];
    #pragma unroll
    for (int i = 0; i < 2; ++i)
        #pragma unroll
        for (int j = 0; j < 4; ++j) acc[i][j] = (f32x4){0.f, 0.f, 0.f, 0.f};

    #pragma unroll
    for (int ks = 0; ks < 2; ++ks)
        #pragma unroll
        for (int rt = 0; rt < 2; ++rt)
            #pragma unroll
            for (int ct = 0; ct < 4; ++ct) {
                acc[rt][ct] = mfma16(ah[rt][ks], b[ks][ct], acc[rt][ct]);
                acc[rt][ct] = mfma16(al[rt][ks], b[ks][ct], acc[rt][ct]);
            }

    #pragma unroll
    for (int rt = 0; rt < 2; ++rt)
        #pragma unroll
        for (int j = 0; j < 4; ++j) {
            int row = p0 + rt * 16 + lq * 4 + j;
            if (row < N) {
                #pragma unroll
                for (int ct = 0; ct < 4; ++ct)
                    O[(size_t)row * 64 + ct * 16 + r] = acc[rt][ct][j];
            }
        }
}

// ---- build body (R15: window probe + 26 independent loads + block-agg emit) ----
static __device__ __forceinline__ void build_body(
    const int* __restrict__ coords, const int* __restrict__ table,
    const unsigned* __restrict__ bitmap,
    int* __restrict__ pin, int* __restrict__ pout, int* __restrict__ cnt,
    int N, int ck, int tid, u64 (*sbal)[4], int (*sbase4)[4])
{
    const int lane = tid & 63, wave = tid >> 6;
    const int n = ck * 256 + tid;
    const bool valid = n < N;

    int4 c = {0, 0, 0, 0};
    if (valid) c = ((const int4*)coords)[n];
    const int z  = c.w;
    const int zb = (z == 0) ? 0 : z - 1;
    const int wofs = zb >> 5, sh = zb & 31;

    unsigned omask = 0;
    #pragma unroll
    for (int cidx = 0; cidx < 9; ++cidx) {
        int dx = cidx / 3 - 1, dy = cidx % 3 - 1;
        int qx = c.y + dx, qy = c.z + dy;
        bool colok = valid && ((unsigned)qx < SGRID) && ((unsigned)qy < SGRID);
        int wi = colok ? ((((c.x * SGRID + qx) * SGRID + qy) << 2) + wofs) : 0;
        unsigned w0 = bitmap[wi];
        unsigned w1 = bitmap[wi + 1];
        u64 w = (u64)w0 | ((u64)w1 << 32);
        unsigned t = (unsigned)(w >> sh) & 7u;
        if (z == 0)         t = (t << 1) & 6u;
        if (z == SGRID - 1) t &= 3u;
        t = colok ? t : 0u;
        omask |= t << (cidx * 3);
    }
    omask &= ~(1u << 13);

    const int key = ((c.x * SGRID + c.y) * SGRID + c.z) * SGRID + z;
    int nb[26];
    #pragma unroll
    for (int s = 0; s < 26; ++s) {
        int o = s < 13 ? s : s + 1;
        bool occ = (omask >> o) & 1u;
        int qkey = key + (o / 9 - 1) * SGRID * SGRID + ((o / 3) % 3 - 1) * SGRID + (o % 3 - 1);
        int v = table[occ ? qkey : 0];
        nb[s] = occ ? v : -1;
    }

    #pragma unroll
    for (int s = 0; s < 26; ++s) {
        u64 bal = __ballot(nb[s] >= 0);
        if (lane == 0) sbal[s][wave] = bal;
    }
    __syncthreads();

    if (tid < 26) {
        int c0 = (int)__popcll(sbal[tid][0]);
        int c1 = (int)__popcll(sbal[tid][1]);
        int c2 = (int)__popcll(sbal[tid][2]);
        int c3 = (int)__popcll(sbal[tid][3]);
        int tot = c0 + c1 + c2 + c3;
        int base = tot ? atomicAdd(&cnt[tid * 16], tot) : 0;
        sbase4[tid][0] = base;
        sbase4[tid][1] = base + c0;
        sbase4[tid][2] = base + c0 + c1;
        sbase4[tid][3] = base + c0 + c1 + c2;
    }
    __syncthreads();

    const u64 ltmask = (1ull << lane) - 1ull;
    #pragma unroll
    for (int s = 0; s < 26; ++s) {
        if (nb[s] >= 0) {
            int pos = sbase4[s][wave] + (int)__popcll(sbal[s][wave] & ltmask);
            if (pos < CAP) {
                pin[s * CAP + pos]  = nb[s];
                pout[s * CAP + pos] = n;
            }
        }
    }
}

static __device__ __forceinline__ void wprep_item(
    const float* __restrict__ W1, const float* __restrict__ W2,
    f16* __restrict__ Wp1, f16* __restrict__ Wp2, int idx)
{
    const int half = 27 * 512;
    const float* W = (idx < half) ? W1 : W2;
    f16* Wp = (idx < half) ? Wp1 : Wp2;
    int id = (idx < half) ? idx : idx - half;
    int lane = id & 63;
    int ks = (id >> 6) & 1;
    int ct = (id >> 7) & 3;
    int o  = id >> 9;
    int co  = ct * 16 + (lane & 15);
    int ci0 = ks * 32 + (lane >> 4) * 8;
    union { f16 h[8]; uint4 u; } hv;
    #pragma unroll
    for (int j = 0; j < 8; ++j)
        hv.h[j] = (f16)W[((size_t)o * 64 + ci0 + j) * 64 + co];
    ((uint4*)Wp)[id] = hv.u;
}

// ---------------- K1: clear bitmap + counters + zero-row ----------------
__global__ void clear_meta(uint4* __restrict__ bitmap4, int nwords4,
                           int* __restrict__ cnt, float* __restrict__ zrow) {
    const int stride = gridDim.x * 256;
    for (int i = blockIdx.x * 256 + threadIdx.x; i < nwords4; i += stride)
        bitmap4[i] = (uint4){0, 0, 0, 0};
    if (blockIdx.x == 0 && threadIdx.x < 26) cnt[threadIdx.x * 16] = 0;
    if (blockIdx.x == 0 && threadIdx.x < 64) zrow[threadIdx.x] = 0.f;
}

// ---------------- K2: scatter + W prep (mixed grid) ----------------
__global__ void __launch_bounds__(256) scatter_prep(
    const int* __restrict__ coords, int* __restrict__ table,
    unsigned* __restrict__ bitmap, int N, int scatB,
    const float* __restrict__ W1, const float* __restrict__ W2,
    f16* __restrict__ Wp1, f16* __restrict__ Wp2)
{
    const int tid = threadIdx.x;
    if (blockIdx.x < scatB) {
        int i = blockIdx.x * 256 + tid;
        if (i < N) {
            int4 c = ((const int4*)coords)[i];
            int key = ((c.x * SGRID + c.y) * SGRID + c.z) * SGRID + c.w;
            table[key] = i;
            atomicOr(&bitmap[key >> 5], 1u << (key & 31));
        }
        return;
    }
    wprep_item(W1, W2, Wp1, Wp2, (blockIdx.x - scatB) * 256 + tid);
}

// ---------------- K3: build (blocks first) + staged center1 ----------------
__global__ void __launch_bounds__(256) build_center(
    const int* __restrict__ coords, const int* __restrict__ table,
    const unsigned* __restrict__ bitmap,
    int* __restrict__ pin, int* __restrict__ pout, int* __restrict__ cnt,
    int N, int probeB,
    const float* __restrict__ F, const f16* __restrict__ Wp, float* __restrict__ H)
{
    __shared__ union {
        float sF[8192];
        struct { u64 sbal[26][4]; int sbase4[26][4]; } pb;
    } sm;

    if (blockIdx.x >= probeB) {
        const int lane = threadIdx.x & 63;
        const uint4* wb = (const uint4*)Wp + 13 * 512 + lane;
        uint4 b[2][4];
        #pragma unroll
        for (int ct = 0; ct < 4; ++ct)
            #pragma unroll
            for (int ks = 0; ks < 2; ++ks)
                b[ks][ct] = wb[(ct * 2 + ks) * 64];
        center_staged(F, b, H, N, (blockIdx.x - probeB) * 4, threadIdx.x, sm.sF);
        return;
    }
    build_body(coords, table, bitmap, pin, pout, cnt, N, blockIdx.x, threadIdx.x,
               sm.pb.sbal, sm.pb.sbase4);
}

// ---------------- K5: staged center (layer 2) ----------------
__global__ void __launch_bounds__(256) conv_center(
    const float* __restrict__ A, const f16* __restrict__ Wp,
    float* __restrict__ O, int N)
{
    __shared__ float sF[8192];
    const int lane = threadIdx.x & 63;
    const uint4* wb = (const uint4*)Wp + 13 * 512 + lane;
    uint4 b[2][4];
    #pragma unroll
    for (int ct = 0; ct < 4; ++ct)
        #pragma unroll
        for (int ks = 0; ks < 2; ++ks)
            b[ks][ct] = wb[(ct * 2 + ks) * 64];
    center_staged(A, b, O, N, blockIdx.x * 4, threadIdx.x, sF);
}

// ---------------- K4/K6: staged sparse taps ----------------
__global__ void __launch_bounds__(256) conv_sparse(
    const float* __restrict__ A, const f16* __restrict__ Wp,
    const int* __restrict__ pin, const int* __restrict__ pout,
    const int* __restrict__ cnt, float* __restrict__ O,
    const float* __restrict__ zrow)
{
    __shared__ float sF[4096];    // 4 waves * 16 rows * 64 floats
    int w = (blockIdx.x * 256 + threadIdx.x) >> 6;
    if (w >= 26 * 512) return;
    const int lane = threadIdx.x & 63;
    const int wv = threadIdx.x >> 6;
    int slot  = w >> 9;
    int rem   = w & 511;
    int chunk = rem >> 1;
    int ch    = rem & 1;
    int cn = cnt[slot * 16]; if (cn > CAP) cn = CAP;
    int i0 = chunk * 16;
    if (i0 >= cn) return;
    int o = slot < 13 ? slot : slot + 1;
    const int r = lane & 15, lq = lane >> 4;
    float* sW = sF + wv * 1024;

    // stage 16 gathered rows (4 async KB in flight; invalid pairs -> zero row)
    #pragma unroll
    for (int i = 0; i < 4; ++i) {
        int rl = i * 4 + (lane >> 4);
        int slotc = lane & 15;
        int csrc = (slotc + rl) & 15;
        int p = i0 + rl;
        const float* src;
        if (p < cn) {
            int rid = pin[slot * CAP + p];
            src = A + (size_t)rid * 64 + csrc * 4;
        } else {
            src = zrow + csrc * 4;
        }
        gload16(src, sW + i * 256);
    }

    const uint4* wb = (const uint4*)Wp + (size_t)o * 512 + lane;
    uint4 b[2][2];
    #pragma unroll
    for (int ct = 0; ct < 2; ++ct)
        #pragma unroll
        for (int ks = 0; ks < 2; ++ks)
            b[ct][ks] = wb[((ch * 2 + ct) * 2 + ks) * 64];

    asm volatile("s_waitcnt vmcnt(0)" ::: "memory");
    __builtin_amdgcn_sched_barrier(0);

    uint4 ah[2], al[2];
    read_row_frags(sW, r, lq, ah, al);

    f32x4 acc[2];
    acc[0] = (f32x4){0.f, 0.f, 0.f, 0.f};
    acc[1] = (f32x4){0.f, 0.f, 0.f, 0.f};
    #pragma unroll
    for (int ks = 0; ks < 2; ++ks)
        #pragma unroll
        for (int ct = 0; ct < 2; ++ct) {
            acc[ct] = mfma16(ah[ks], b[ct][ks], acc[ct]);
            acc[ct] = mfma16(al[ks], b[ct][ks], acc[ct]);
        }

    #pragma unroll
    for (int j = 0; j < 4; ++j) {
        int pr = i0 + lq * 4 + j;
        if (pr < cn) {
            int oidx = pout[slot * CAP + pr];
            #pragma unroll
            for (int ct = 0; ct < 2; ++ct)
                atomicAdd(&O[(size_t)oidx * 64 + (ch * 2 + ct) * 16 + r], acc[ct][j]);
        }
    }
}

extern "C" void kernel_launch(void* const* d_in, const int* in_sizes, int n_in,
                              void* d_out, int out_size, void* d_ws, size_t ws_size,
                              hipStream_t stream) {
    const float* feats  = (const float*)d_in[0];
    const int*   coords = (const int*)d_in[1];
    const float* W1     = (const float*)d_in[2];
    const float* W2     = (const float*)d_in[3];
    float* out = (float*)d_out;

    const int N = in_sizes[0] / 64;
    const size_t nvox = 2ull * SGRID * SGRID * SGRID;

    char* p = (char*)d_ws;
    int*      table  = (int*)p;      p += nvox * 4;          // no init (bitmap-guarded)
    unsigned* bitmap = (unsigned*)p; p += (nvox / 32) * 4;   // 524 KB
    p += 16;                                                  // pad word (window overread)
    int*      cnt    = (int*)p;      p += 26 * 16 * 4;
    float*    zrow   = (float*)p;    p += 64 * 4;            // zeroed dummy row
    int*      pin    = (int*)p;      p += 26ull * CAP * 4;
    int*      pout   = (int*)p;      p += 26ull * CAP * 4;
    float*    H      = (float*)p;    p += (size_t)N * 64 * 4;
    f16*      Wp1    = (f16*)p;      p += 27ull * 4096 * 2;
    f16*      Wp2    = (f16*)p;      p += 27ull * 4096 * 2;

    const int bm4     = (int)(nvox / 32 / 4) + 1;
    const int scatB   = (N + 255) / 256;                 // 391
    const int ngroups = (N + 31) / 32;
    const int centerB = (ngroups + 3) / 4;               // 782 (4 groups/block)
    const int sparseB = 26 * 512 / 4;                    // 3328

    clear_meta<<<256, 256, 0, stream>>>((uint4*)bitmap, bm4, cnt, zrow);
    scatter_prep<<<scatB + 108, 256, 0, stream>>>(coords, table, bitmap, N, scatB,
                                                  W1, W2, Wp1, Wp2);
    build_center<<<scatB + centerB, 256, 0, stream>>>(coords, table, bitmap,
                                                      pin, pout, cnt, N, scatB,
                                                      feats, Wp1, H);
    conv_sparse<<<sparseB, 256, 0, stream>>>(feats, Wp1, pin, pout, cnt, H, zrow);
    conv_center<<<centerB, 256, 0, stream>>>(H, Wp2, out, N);
    conv_sparse<<<sparseB, 256, 0, stream>>>(H, Wp2, pin, pout, cnt, out, zrow);
}